// Round 5
// baseline (186.294 us; speedup 1.0000x reference)
//
#include <hip/hip_runtime.h>

#define BATCH 1024
#define VS 600          // V*S = 20*30
#define D 128
#define H0 256
#define H1 128
#define NCLASS 20
#define CAP 128         // per-(sample,pool,owner) bucket capacity; Binomial(600,1/8) ~ 75 +- 8, P(>128)~1e-11

// ws layout:
//   part:   float [8 * BATCH * 256]        = 8 MB     (owner-partial pooled vectors)
//   lists:  ushort[BATCH * 16 * CAP]       = 4 MB     (bucketed row ids, row>>3)
//   counts: int   [BATCH * 16]             = 64 KB

// ---------------- K0: bucket indices by owner (row & 7) ----------------
// One block per sample. Reads the 1200 indices ONCE, scatters compact
// per-(pool,owner) lists so K1 never re-reads raw indices 8x across XCDs.
__global__ __launch_bounds__(256) void bucket_kernel(
    const int* __restrict__ diag_idx, const int* __restrict__ proc_idx,
    unsigned short* __restrict__ lists, int* __restrict__ counts)
{
    __shared__ int cnt[16];
    const int s = blockIdx.x, tid = threadIdx.x;
    if (tid < 16) cnt[tid] = 0;
    __syncthreads();

    const int* dsrc = diag_idx + s * VS;
    const int* psrc = proc_idx + s * VS;
    for (int i = tid; i < VS; i += 256) {
        const int r = dsrc[i];                  // diag -> buckets 0..7
        const int b = r & 7;
        const int pos = atomicAdd(&cnt[b], 1);
        if (pos < CAP) lists[(s * 16 + b) * CAP + pos] = (unsigned short)(r >> 3);
        const int r2 = psrc[i];                 // proc -> buckets 8..15
        const int b2 = 8 + (r2 & 7);
        const int pos2 = atomicAdd(&cnt[b2], 1);
        if (pos2 < CAP) lists[(s * 16 + b2) * CAP + pos2] = (unsigned short)(r2 >> 3);
    }
    __syncthreads();
    if (tid < 16) counts[s * 16 + tid] = min(cnt[tid], CAP);
}

// ---------------- K1: per-(sample, owner) partial gather-pool ----------------
// Grid 8192 = (sample s = bid>>3, owner x = bid&7); bid%8 -> XCD x (heuristic,
// correctness mapping-independent). Rows with row&7==x live in one L2 only.
__global__ __launch_bounds__(256) void gather_partial_kernel(
    const unsigned short* __restrict__ lists, const int* __restrict__ counts,
    const float* __restrict__ emb, float* __restrict__ part)
{
    __shared__ unsigned short lq[2 * CAP];                    // diag + proc bucket
    __shared__ int c2[2];
    __shared__ __attribute__((aligned(16))) float red[8][D];  // 4 KB

    const int bid = blockIdx.x;
    const int x   = bid & 7;
    const int s   = bid >> 3;
    const int tid = threadIdx.x;

    if (tid < 2) c2[tid] = counts[s * 16 + tid * 8 + x];
    if (tid < CAP)           lq[tid] = lists[(s * 16 + x) * CAP + tid];
    else if (tid < 2 * CAP)  lq[tid] = lists[(s * 16 + 8 + x) * CAP + (tid - CAP)];
    __syncthreads();

    // 8 groups of 32 lanes: groups 0-3 diag, 4-7 proc. Lane l = float4 cols
    // [4l,4l+3] -> one row per group-iter is a coalesced 512B.
    const int grp = tid >> 5, lane = tid & 31;
    const int pool = grp >> 2, sub = grp & 3;
    const int cnt = c2[pool];
    const unsigned short* lp = lq + pool * CAP;
    float4 acc = make_float4(0.f, 0.f, 0.f, 0.f);
    #pragma unroll 4
    for (int i = sub; i < cnt; i += 4) {
        const int row = ((int)lp[i] << 3) | x;     // reconstruct row id
        const float4 e = ((const float4*)(emb + row * D))[lane];
        acc.x += e.x; acc.y += e.y; acc.z += e.z; acc.w += e.w;
    }
    ((float4*)red[grp])[lane] = acc;
    __syncthreads();

    // reduce 4 groups per pool -> 256-float partial, pre-scaled by 1/30
    {
        const int p = tid >> 7, d = tid & 127;
        const float v = red[p*4+0][d] + red[p*4+1][d] + red[p*4+2][d] + red[p*4+3][d];
        part[(x * BATCH + s) * (2 * D) + tid] = v * (1.0f / 30.0f);
    }
}

// ---------------- K2: reduce partials + fused MLP, 8 samples per block ----------------
// W rows are loaded once into registers and reused across 8 samples; the
// x/h operands are LDS broadcasts (same address across lanes -> conflict-free).
__global__ __launch_bounds__(256) void mlp_kernel(
    const float* __restrict__ part,
    const float* __restrict__ W0, const float* __restrict__ b0,
    const float* __restrict__ W1, const float* __restrict__ b1,
    const float* __restrict__ W2, const float* __restrict__ b2,
    float* __restrict__ out)
{
    __shared__ __attribute__((aligned(16))) float xs [8][2 * D];  // 8 KB
    __shared__ __attribute__((aligned(16))) float h0s[8][H0];     // 8 KB
    __shared__ __attribute__((aligned(16))) float h1s[8][H1];     // 4 KB

    const int s0 = blockIdx.x * 8, tid = threadIdx.x;

    // gather + reduce the 8 owner partials for 8 samples
    #pragma unroll
    for (int j = 0; j < 8; ++j) {
        float v = 0.f;
        #pragma unroll
        for (int xp = 0; xp < 8; ++xp)
            v += part[(xp * BATCH + s0 + j) * (2 * D) + tid];
        xs[j][tid] = v;
    }
    __syncthreads();

    // fc0 (256 -> 256): thread = output row, 8 samples in registers
    {
        const float4* wrow = (const float4*)(W0 + tid * (2 * D));
        float a[8];
        #pragma unroll
        for (int j = 0; j < 8; ++j) a[j] = b0[tid];
        for (int k = 0; k < 64; ++k) {
            const float4 w = wrow[k];
            #pragma unroll
            for (int j = 0; j < 8; ++j) {
                const float4 xx = ((const float4*)xs[j])[k];
                a[j] += w.x * xx.x + w.y * xx.y + w.z * xx.z + w.w * xx.w;
            }
        }
        #pragma unroll
        for (int j = 0; j < 8; ++j) h0s[j][tid] = fmaxf(a[j], 0.f);  // relu before fc1
    }
    __syncthreads();

    // fc1 (256 -> 128)
    if (tid < H1) {
        const float4* wrow = (const float4*)(W1 + tid * H0);
        float a[8];
        #pragma unroll
        for (int j = 0; j < 8; ++j) a[j] = b1[tid];
        for (int k = 0; k < 64; ++k) {
            const float4 w = wrow[k];
            #pragma unroll
            for (int j = 0; j < 8; ++j) {
                const float4 hh = ((const float4*)h0s[j])[k];
                a[j] += w.x * hh.x + w.y * hh.y + w.z * hh.z + w.w * hh.w;
            }
        }
        #pragma unroll
        for (int j = 0; j < 8; ++j) h1s[j][tid] = fmaxf(a[j], 0.f);  // relu before fc2
    }
    __syncthreads();

    // fc2 (128 -> 20), no relu: thread = (row, sample)
    if (tid < 8 * NCLASS) {
        const int row = tid >> 3, j = tid & 7;
        const float4* wrow = (const float4*)(W2 + row * H1);
        float a = b2[row];
        for (int k = 0; k < 32; ++k) {
            const float4 w = wrow[k];
            const float4 hh = ((const float4*)h1s[j])[k];
            a += w.x * hh.x + w.y * hh.y + w.z * hh.z + w.w * hh.w;
        }
        out[(s0 + j) * NCLASS + row] = a;
    }
}

extern "C" void kernel_launch(void* const* d_in, const int* in_sizes, int n_in,
                              void* d_out, int out_size, void* d_ws, size_t ws_size,
                              hipStream_t stream) {
    const int*   diag_idx = (const int*)d_in[0];
    const int*   proc_idx = (const int*)d_in[1];
    const float* emb      = (const float*)d_in[2];
    const float* W0       = (const float*)d_in[3];
    const float* b0       = (const float*)d_in[4];
    const float* W1       = (const float*)d_in[5];
    const float* b1       = (const float*)d_in[6];
    const float* W2       = (const float*)d_in[7];
    const float* b2       = (const float*)d_in[8];
    float* out = (float*)d_out;

    char* ws = (char*)d_ws;
    float*          part   = (float*)ws;                          // 8 MB
    unsigned short* lists  = (unsigned short*)(ws + 8*1024*1024); // 4 MB
    int*            counts = (int*)(ws + 12*1024*1024);           // 64 KB

    bucket_kernel<<<BATCH, 256, 0, stream>>>(diag_idx, proc_idx, lists, counts);
    gather_partial_kernel<<<8 * BATCH, 256, 0, stream>>>(lists, counts, emb, part);
    mlp_kernel<<<BATCH / 8, 256, 0, stream>>>(part, W0, b0, W1, b1, W2, b2, out);
}

// Round 6
// 153.948 us; speedup vs baseline: 1.2101x; 1.2101x over previous
//
#include <hip/hip_runtime.h>

#define BATCH 1024
#define VS 600          // V*S = 20*30
#define D 128
#define H0 256
#define H1 128
#define NCLASS 20
#define CAP 128         // per-(sample,pool,owner) bucket capacity; Binomial(600,1/8) ~ 75 +- 8, P(>128)~1e-11
#define SPB 4           // samples per MLP block

// ws layout:
//   part:   float [8 * BATCH * 256]        = 8 MB     (owner-partial pooled vectors)
//   lists:  ushort[BATCH * 16 * CAP]       = 4 MB     (bucketed row ids, row>>3)
//   counts: int   [BATCH * 16]             = 64 KB

// ---------------- K0: bucket indices by owner (row & 7) ----------------
__global__ __launch_bounds__(256) void bucket_kernel(
    const int* __restrict__ diag_idx, const int* __restrict__ proc_idx,
    unsigned short* __restrict__ lists, int* __restrict__ counts)
{
    __shared__ int cnt[16];
    const int s = blockIdx.x, tid = threadIdx.x;
    if (tid < 16) cnt[tid] = 0;
    __syncthreads();

    const int* dsrc = diag_idx + s * VS;
    const int* psrc = proc_idx + s * VS;
    for (int i = tid; i < VS; i += 256) {
        const int r = dsrc[i];                  // diag -> buckets 0..7
        const int b = r & 7;
        const int pos = atomicAdd(&cnt[b], 1);
        if (pos < CAP) lists[(s * 16 + b) * CAP + pos] = (unsigned short)(r >> 3);
        const int r2 = psrc[i];                 // proc -> buckets 8..15
        const int b2 = 8 + (r2 & 7);
        const int pos2 = atomicAdd(&cnt[b2], 1);
        if (pos2 < CAP) lists[(s * 16 + b2) * CAP + pos2] = (unsigned short)(r2 >> 3);
    }
    __syncthreads();
    if (tid < 16) counts[s * 16 + tid] = min(cnt[tid], CAP);
}

// ---------------- K1: per-(sample, owner) partial gather-pool ----------------
// Grid 8192 = (sample s = bid>>3, owner x = bid&7); bid%8 -> XCD x (heuristic,
// correctness mapping-independent). Rows with row&7==x live in one L2 only.
__global__ __launch_bounds__(256) void gather_partial_kernel(
    const unsigned short* __restrict__ lists, const int* __restrict__ counts,
    const float* __restrict__ emb, float* __restrict__ part)
{
    __shared__ unsigned short lq[2 * CAP];
    __shared__ int c2[2];
    __shared__ __attribute__((aligned(16))) float red[8][D];

    const int bid = blockIdx.x;
    const int x   = bid & 7;
    const int s   = bid >> 3;
    const int tid = threadIdx.x;

    if (tid < 2) c2[tid] = counts[s * 16 + tid * 8 + x];
    if (tid < CAP)           lq[tid] = lists[(s * 16 + x) * CAP + tid];
    else if (tid < 2 * CAP)  lq[tid] = lists[(s * 16 + 8 + x) * CAP + (tid - CAP)];
    __syncthreads();

    const int grp = tid >> 5, lane = tid & 31;
    const int pool = grp >> 2, sub = grp & 3;
    const int cnt = c2[pool];
    const unsigned short* lp = lq + pool * CAP;
    float4 acc = make_float4(0.f, 0.f, 0.f, 0.f);
    #pragma unroll 4
    for (int i = sub; i < cnt; i += 4) {
        const int row = ((int)lp[i] << 3) | x;     // reconstruct row id
        const float4 e = ((const float4*)(emb + row * D))[lane];
        acc.x += e.x; acc.y += e.y; acc.z += e.z; acc.w += e.w;
    }
    ((float4*)red[grp])[lane] = acc;
    __syncthreads();

    {
        const int p = tid >> 7, d = tid & 127;
        const float v = red[p*4+0][d] + red[p*4+1][d] + red[p*4+2][d] + red[p*4+3][d];
        part[(x * BATCH + s) * (2 * D) + tid] = v * (1.0f / 30.0f);
    }
}

// ---------------- K2: reduce partials + fused MLP ----------------
// 4 samples/block, 512 threads, 256 blocks (one per CU, 8 waves/CU).
// Dots split across 2-4 lanes (shfl_xor reduce) to shorten the serial chain;
// W rows reused across 4 samples in registers; x/h from LDS broadcast.
__global__ __launch_bounds__(512) void mlp_kernel(
    const float* __restrict__ part,
    const float* __restrict__ W0, const float* __restrict__ b0,
    const float* __restrict__ W1, const float* __restrict__ b1,
    const float* __restrict__ W2, const float* __restrict__ b2,
    float* __restrict__ out)
{
    __shared__ __attribute__((aligned(16))) float xs [SPB][2 * D];  // 4 KB
    __shared__ __attribute__((aligned(16))) float h0s[SPB][H0];     // 4 KB
    __shared__ __attribute__((aligned(16))) float h1s[SPB][H1];     // 2 KB

    const int s0 = blockIdx.x * SPB, tid = threadIdx.x;

    // reduce the 8 owner partials for SPB samples (SPB*256 elems over 512 thr)
    #pragma unroll
    for (int t = tid; t < SPB * 2 * D; t += 512) {
        const int j = t >> 8, d = t & 255;
        float v = 0.f;
        #pragma unroll
        for (int xp = 0; xp < 8; ++xp)
            v += part[(xp * BATCH + s0 + j) * (2 * D) + d];
        xs[j][d] = v;
    }
    __syncthreads();

    // fc0 (512 -> 256 rows): 2 lanes per row (k-halves)
    {
        const int row = tid >> 1, half = tid & 1;
        const float4* wrow = (const float4*)(W0 + row * (2 * D) + half * D);
        const int xoff = half * (D / 4);
        float a[SPB];
        #pragma unroll
        for (int j = 0; j < SPB; ++j) a[j] = 0.f;
        #pragma unroll 4
        for (int k = 0; k < 32; ++k) {
            const float4 w = wrow[k];
            #pragma unroll
            for (int j = 0; j < SPB; ++j) {
                const float4 xx = ((const float4*)xs[j])[xoff + k];
                a[j] += w.x * xx.x + w.y * xx.y + w.z * xx.z + w.w * xx.w;
            }
        }
        #pragma unroll
        for (int j = 0; j < SPB; ++j) {
            a[j] += __shfl_xor(a[j], 1);
            if (!half) h0s[j][row] = fmaxf(a[j] + b0[row], 0.f);  // relu before fc1
        }
    }
    __syncthreads();

    // fc1 (256 -> 128 rows): 4 lanes per row (k-quarters)
    {
        const int row = tid >> 2, q = tid & 3;
        const float4* wrow = (const float4*)(W1 + row * H0 + q * 64);
        const int hoff = q * 16;
        float a[SPB];
        #pragma unroll
        for (int j = 0; j < SPB; ++j) a[j] = 0.f;
        #pragma unroll 4
        for (int k = 0; k < 16; ++k) {
            const float4 w = wrow[k];
            #pragma unroll
            for (int j = 0; j < SPB; ++j) {
                const float4 hh = ((const float4*)h0s[j])[hoff + k];
                a[j] += w.x * hh.x + w.y * hh.y + w.z * hh.z + w.w * hh.w;
            }
        }
        #pragma unroll
        for (int j = 0; j < SPB; ++j) {
            a[j] += __shfl_xor(a[j], 1);
            a[j] += __shfl_xor(a[j], 2);
            if (!q) h1s[j][row] = fmaxf(a[j] + b1[row], 0.f);     // relu before fc2
        }
    }
    __syncthreads();

    // fc2 (128 -> 20 rows): tid = row<<4 | q<<2 | j; 4 lanes per (row,j)
    if (tid < NCLASS * 16) {
        const int row = tid >> 4, q = (tid >> 2) & 3, j = tid & 3;
        const float4* wrow = (const float4*)(W2 + row * H1 + q * 32);
        const float4* hv   = (const float4*)(h1s[j] + q * 32);
        float a = 0.f;
        #pragma unroll
        for (int k = 0; k < 8; ++k) {
            const float4 w = wrow[k], hh = hv[k];
            a += w.x * hh.x + w.y * hh.y + w.z * hh.z + w.w * hh.w;
        }
        a += __shfl_xor(a, 4);
        a += __shfl_xor(a, 8);
        if (!q) out[(s0 + j) * NCLASS + row] = a + b2[row];
    }
}

extern "C" void kernel_launch(void* const* d_in, const int* in_sizes, int n_in,
                              void* d_out, int out_size, void* d_ws, size_t ws_size,
                              hipStream_t stream) {
    const int*   diag_idx = (const int*)d_in[0];
    const int*   proc_idx = (const int*)d_in[1];
    const float* emb      = (const float*)d_in[2];
    const float* W0       = (const float*)d_in[3];
    const float* b0       = (const float*)d_in[4];
    const float* W1       = (const float*)d_in[5];
    const float* b1       = (const float*)d_in[6];
    const float* W2       = (const float*)d_in[7];
    const float* b2       = (const float*)d_in[8];
    float* out = (float*)d_out;

    char* ws = (char*)d_ws;
    float*          part   = (float*)ws;                          // 8 MB
    unsigned short* lists  = (unsigned short*)(ws + 8*1024*1024); // 4 MB
    int*            counts = (int*)(ws + 12*1024*1024);           // 64 KB

    bucket_kernel<<<BATCH, 256, 0, stream>>>(diag_idx, proc_idx, lists, counts);
    gather_partial_kernel<<<8 * BATCH, 256, 0, stream>>>(lists, counts, emb, part);
    mlp_kernel<<<BATCH / SPB, 512, 0, stream>>>(part, W0, b0, W1, b1, W2, b2, out);
}

// Round 7
// 150.760 us; speedup vs baseline: 1.2357x; 1.0211x over previous
//
#include <hip/hip_runtime.h>

#define BATCH 1024
#define VS 600          // V*S = 20*30
#define D 128
#define H0 256
#define H1 128
#define NCLASS 20
#define CAP 128         // per-(sample,pool,owner) bucket capacity; Binomial(600,1/8) ~ 75 +- 8, P(>128)~1e-11
#define SPB 4           // samples per MLP block

// ws layout:
//   part:   float [16 * BATCH * 128]       = 8 MB   ((half,owner)-partial pooled vectors)
//   lists:  ushort[BATCH * 16 * CAP]       = 4 MB   (bucketed row ids, row>>3)
//   counts: int   [BATCH * 16]             = 64 KB

// ---------------- K0: bucket indices by owner (row & 7) ----------------
__global__ __launch_bounds__(256) void bucket_kernel(
    const int* __restrict__ diag_idx, const int* __restrict__ proc_idx,
    unsigned short* __restrict__ lists, int* __restrict__ counts)
{
    __shared__ int cnt[16];
    const int s = blockIdx.x, tid = threadIdx.x;
    if (tid < 16) cnt[tid] = 0;
    __syncthreads();

    const int* dsrc = diag_idx + s * VS;
    const int* psrc = proc_idx + s * VS;
    for (int i = tid; i < VS; i += 256) {
        const int r = dsrc[i];                  // diag -> buckets 0..7
        const int b = r & 7;
        const int pos = atomicAdd(&cnt[b], 1);
        if (pos < CAP) lists[(s * 16 + b) * CAP + pos] = (unsigned short)(r >> 3);
        const int r2 = psrc[i];                 // proc -> buckets 8..15
        const int b2 = 8 + (r2 & 7);
        const int pos2 = atomicAdd(&cnt[b2], 1);
        if (pos2 < CAP) lists[(s * 16 + b2) * CAP + pos2] = (unsigned short)(r2 >> 3);
    }
    __syncthreads();
    if (tid < 16) counts[s * 16 + tid] = min(cnt[tid], CAP);
}

// ---------------- K1: per-(sample, owner, col-half) partial gather-pool ----------------
// Two stream-serialized passes h=0,1 over cols [h*64, h*64+64). Per pass an
// XCD's working set is 12500 rows x 256B = 3.2 MB < 4 MB L2 -> capacity
// misses ~0. Grid 8192 = (s = bid>>3, owner x = bid&7); bid%8 -> XCD x.
__global__ __launch_bounds__(256) void gather_partial_kernel(
    const unsigned short* __restrict__ lists, const int* __restrict__ counts,
    const float* __restrict__ emb, float* __restrict__ part, const int h)
{
    __shared__ unsigned short lq[2 * CAP];
    __shared__ int c2[2];
    __shared__ __attribute__((aligned(16))) float red[16][64];   // 4 KB

    const int bid = blockIdx.x;
    const int x   = bid & 7;
    const int s   = bid >> 3;
    const int tid = threadIdx.x;

    if (tid < 2) c2[tid] = counts[s * 16 + tid * 8 + x];
    if (tid < CAP)           lq[tid] = lists[(s * 16 + x) * CAP + tid];
    else if (tid < 2 * CAP)  lq[tid] = lists[(s * 16 + 8 + x) * CAP + (tid - CAP)];
    __syncthreads();

    // 16 groups of 16 lanes: groups 0-7 diag, 8-15 proc. Lane l = float4 at
    // cols [h*64 + 4l, ...+3] -> one half-row per group-iter = coalesced 256B.
    const int grp = tid >> 4, lane = tid & 15;
    const int pool = grp >> 3, sub = grp & 7;
    const int cnt = c2[pool];
    const unsigned short* lp = lq + pool * CAP;
    const float* embh = emb + h * 64;
    float4 acc = make_float4(0.f, 0.f, 0.f, 0.f);
    #pragma unroll 4
    for (int i = sub; i < cnt; i += 8) {
        const int row = ((int)lp[i] << 3) | x;     // reconstruct row id
        const float4 e = ((const float4*)(embh + row * D))[lane];
        acc.x += e.x; acc.y += e.y; acc.z += e.z; acc.w += e.w;
    }
    ((float4*)red[grp])[lane] = acc;
    __syncthreads();

    // reduce 8 groups per pool -> 128-float partial, pre-scaled by 1/30
    if (tid < 128) {
        const int p = tid >> 6, c = tid & 63;
        float v = 0.f;
        #pragma unroll
        for (int g = 0; g < 8; ++g) v += red[p * 8 + g][c];
        part[((h * 8 + x) * BATCH + s) * 128 + p * 64 + c] = v * (1.0f / 30.0f);
    }
}

// ---------------- K2: reduce partials + fused MLP ----------------
// 4 samples/block, 512 threads, 256 blocks (one per CU, 8 waves/CU).
__global__ __launch_bounds__(512) void mlp_kernel(
    const float* __restrict__ part,
    const float* __restrict__ W0, const float* __restrict__ b0,
    const float* __restrict__ W1, const float* __restrict__ b1,
    const float* __restrict__ W2, const float* __restrict__ b2,
    float* __restrict__ out)
{
    __shared__ __attribute__((aligned(16))) float xs [SPB][2 * D];  // 4 KB
    __shared__ __attribute__((aligned(16))) float h0s[SPB][H0];     // 4 KB
    __shared__ __attribute__((aligned(16))) float h1s[SPB][H1];     // 2 KB

    const int s0 = blockIdx.x * SPB, tid = threadIdx.x;

    // reduce the 16 (half,owner) partials for SPB samples
    // output dim d in [0,256): pool p=d>>7, col=d&127, half hh=col>>6, c=col&63
    #pragma unroll
    for (int t = tid; t < SPB * 2 * D; t += 512) {
        const int j = t >> 8, d = t & 255;
        const int p = d >> 7, col = d & 127, hh = col >> 6, c = col & 63;
        float v = 0.f;
        #pragma unroll
        for (int xp = 0; xp < 8; ++xp)
            v += part[((hh * 8 + xp) * BATCH + s0 + j) * 128 + p * 64 + c];
        xs[j][d] = v;
    }
    __syncthreads();

    // fc0 (512 -> 256 rows): 2 lanes per row (k-halves)
    {
        const int row = tid >> 1, half = tid & 1;
        const float4* wrow = (const float4*)(W0 + row * (2 * D) + half * D);
        const int xoff = half * (D / 4);
        float a[SPB];
        #pragma unroll
        for (int j = 0; j < SPB; ++j) a[j] = 0.f;
        #pragma unroll 4
        for (int k = 0; k < 32; ++k) {
            const float4 w = wrow[k];
            #pragma unroll
            for (int j = 0; j < SPB; ++j) {
                const float4 xx = ((const float4*)xs[j])[xoff + k];
                a[j] += w.x * xx.x + w.y * xx.y + w.z * xx.z + w.w * xx.w;
            }
        }
        #pragma unroll
        for (int j = 0; j < SPB; ++j) {
            a[j] += __shfl_xor(a[j], 1);
            if (!half) h0s[j][row] = fmaxf(a[j] + b0[row], 0.f);  // relu before fc1
        }
    }
    __syncthreads();

    // fc1 (256 -> 128 rows): 4 lanes per row (k-quarters)
    {
        const int row = tid >> 2, q = tid & 3;
        const float4* wrow = (const float4*)(W1 + row * H0 + q * 64);
        const int hoff = q * 16;
        float a[SPB];
        #pragma unroll
        for (int j = 0; j < SPB; ++j) a[j] = 0.f;
        #pragma unroll 4
        for (int k = 0; k < 16; ++k) {
            const float4 w = wrow[k];
            #pragma unroll
            for (int j = 0; j < SPB; ++j) {
                const float4 hh = ((const float4*)h0s[j])[hoff + k];
                a[j] += w.x * hh.x + w.y * hh.y + w.z * hh.z + w.w * hh.w;
            }
        }
        #pragma unroll
        for (int j = 0; j < SPB; ++j) {
            a[j] += __shfl_xor(a[j], 1);
            a[j] += __shfl_xor(a[j], 2);
            if (!q) h1s[j][row] = fmaxf(a[j] + b1[row], 0.f);     // relu before fc2
        }
    }
    __syncthreads();

    // fc2 (128 -> 20 rows): tid = row<<4 | q<<2 | j; 4 lanes per (row,j)
    if (tid < NCLASS * 16) {
        const int row = tid >> 4, q = (tid >> 2) & 3, j = tid & 3;
        const float4* wrow = (const float4*)(W2 + row * H1 + q * 32);
        const float4* hv   = (const float4*)(h1s[j] + q * 32);
        float a = 0.f;
        #pragma unroll
        for (int k = 0; k < 8; ++k) {
            const float4 w = wrow[k], hh = hv[k];
            a += w.x * hh.x + w.y * hh.y + w.z * hh.z + w.w * hh.w;
        }
        a += __shfl_xor(a, 4);
        a += __shfl_xor(a, 8);
        if (!q) out[(s0 + j) * NCLASS + row] = a + b2[row];
    }
}

extern "C" void kernel_launch(void* const* d_in, const int* in_sizes, int n_in,
                              void* d_out, int out_size, void* d_ws, size_t ws_size,
                              hipStream_t stream) {
    const int*   diag_idx = (const int*)d_in[0];
    const int*   proc_idx = (const int*)d_in[1];
    const float* emb      = (const float*)d_in[2];
    const float* W0       = (const float*)d_in[3];
    const float* b0       = (const float*)d_in[4];
    const float* W1       = (const float*)d_in[5];
    const float* b1       = (const float*)d_in[6];
    const float* W2       = (const float*)d_in[7];
    const float* b2       = (const float*)d_in[8];
    float* out = (float*)d_out;

    char* ws = (char*)d_ws;
    float*          part   = (float*)ws;                          // 8 MB
    unsigned short* lists  = (unsigned short*)(ws + 8*1024*1024); // 4 MB
    int*            counts = (int*)(ws + 12*1024*1024);           // 64 KB

    bucket_kernel<<<BATCH, 256, 0, stream>>>(diag_idx, proc_idx, lists, counts);
    gather_partial_kernel<<<8 * BATCH, 256, 0, stream>>>(lists, counts, emb, part, 0);
    gather_partial_kernel<<<8 * BATCH, 256, 0, stream>>>(lists, counts, emb, part, 1);
    mlp_kernel<<<BATCH / SPB, 512, 0, stream>>>(part, W0, b0, W1, b1, W2, b2, out);
}